// Round 5
// baseline (105.949 us; speedup 1.0000x reference)
//
#include <hip/hip_runtime.h>
#include <math.h>

// Problem constants (from reference): cost [B, D, H, W] fp32, k=2.
constexpr int B = 16, D = 48, H = 256, W = 512;
constexpr int HW = H * W;            // 131072 = 2^17
constexpr int PIX = B * HW;          // 2,097,152 pixels
constexpr int BLOCK = 256;           // 4 waves
constexpr int PXB = 2048;            // pixels per block (512 px per wave)
constexpr int SLOTS = 4;             // per-wave ring depth (slices in flight)
constexpr int GRID = PIX / PXB;      // 1024 blocks -> 4 blocks/CU

typedef float f32x4 __attribute__((ext_vector_type(4)));

template <int N>
__device__ __forceinline__ void waitvm() {
    asm volatile("s_waitcnt vmcnt(%0)" ::"i"(N) : "memory");
}
__device__ __forceinline__ void waitlgkm0() {
    asm volatile("s_waitcnt lgkmcnt(0)" ::: "memory");
}

// async global->LDS, 16 B per lane.
// gp: PER-LANE global source address. lp: WAVE-UNIFORM LDS base; HW writes
// lane i's 16 B at lp + 16*i. (m97/m104 semantics.)
#define GLD_LDS16(gp, lp)                                          \
    __builtin_amdgcn_global_load_lds(                              \
        (const __attribute__((address_space(1))) void*)(gp),      \
        (__attribute__((address_space(3))) void*)(lp), 16, 0, 0)

__global__ __launch_bounds__(BLOCK) void topk2_disp_kernel(
    const float* __restrict__ cost, float* __restrict__ out) {
    // [SLOTS][4 waves][512 floats] — each wave touches ONLY its own 2 KiB
    // region of each slot => no cross-wave hazards => no barriers.
    __shared__ __align__(16) float lds[SLOTS * PXB];

    const int t = threadIdx.x;
    const int w = t >> 6;                  // wave id 0..3
    const int l = t & 63;                  // lane
    const int pbase = blockIdx.x * PXB;    // PXB divides HW, block stays in one b
    const int b = pbase >> 17;             // pbase / HW
    const int rem = pbase & (HW - 1);

    // lane's group-0 pixel offset within the block chunk (floats)
    const int lofs = w * 512 + l * 4;
    // per-lane global source for slice d: gsrc + d*HW (group 1: +256)
    const float* gsrc = cost + (size_t)b * D * HW + rem + lofs;
    // wave's region within slot 0 (floats); slot s adds s*PXB
    float* lwb = &lds[w * 512];

    float v1[8], v2[8];
    int i1[8], i2[8];
#pragma unroll
    for (int j = 0; j < 8; ++j) {
        v1[j] = -INFINITY; v2[j] = -INFINITY; i1[j] = 0; i2[j] = 0;
    }

    // prologue: stage slices 0..SLOTS-1 (2 loads each => 8 outstanding)
#pragma unroll
    for (int s = 0; s < SLOTS; ++s) {
        const float* g = gsrc + (size_t)s * HW;      // per-lane address
        GLD_LDS16(g,       lwb + s * PXB);           // group 0 -> [0,256)
        GLD_LDS16(g + 256, lwb + s * PXB + 256);     // group 1 -> [256,512)
    }

    auto consume = [&](int d, int slot) {
        const f32x4 A  = *reinterpret_cast<const f32x4*>(&lds[slot * PXB + lofs]);
        const f32x4 Bv = *reinterpret_cast<const f32x4*>(&lds[slot * PXB + lofs + 256]);
        float x[8] = {A.x, A.y, A.z, A.w, Bv.x, Bv.y, Bv.z, Bv.w};
#pragma unroll
        for (int j = 0; j < 8; ++j) {
            // strict > : ties keep the earlier (lower) index, matching lax.top_k
            if (x[j] > v1[j]) {
                v2[j] = v1[j]; i2[j] = i1[j];
                v1[j] = x[j];  i1[j] = d;
            } else if (x[j] > v2[j]) {
                v2[j] = x[j];  i2[j] = d;
            }
        }
    };

    // main loop: slice d is ready when outstanding loads <= 2*(SLOTS-1)
    for (int d = 0; d < D - SLOTS; ++d) {  // 0..43
        waitvm<2 * (SLOTS - 1)>();         // vmcnt(6): slice d landed
        consume(d, d & (SLOTS - 1));
        waitlgkm0();                       // ds_reads done before DMA overwrite
        const float* g = gsrc + (size_t)(d + SLOTS) * HW;  // per-lane address
        GLD_LDS16(g,       lwb + (d & (SLOTS - 1)) * PXB);
        GLD_LDS16(g + 256, lwb + (d & (SLOTS - 1)) * PXB + 256);
    }
    // tail: drain ring (no more stages)
    waitvm<6>(); consume(44, 0);
    waitvm<4>(); consume(45, 1);
    waitvm<2>(); consume(46, 2);
    waitvm<0>(); consume(47, 3);

    float res[8];
#pragma unroll
    for (int j = 0; j < 8; ++j) {
        // softmax over [v1, v2], v1 >= v2: e = exp(v2-v1)
        const float e   = expf(v2[j] - v1[j]);
        const float inv = 1.0f / (1.0f + e);
        res[j] = ((float)i1[j] + e * (float)i2[j]) * inv;
    }
    f32x4 o0 = {res[0], res[1], res[2], res[3]};
    f32x4 o1 = {res[4], res[5], res[6], res[7]};
    __builtin_nontemporal_store(o0, reinterpret_cast<f32x4*>(out + pbase + lofs));
    __builtin_nontemporal_store(o1, reinterpret_cast<f32x4*>(out + pbase + lofs + 256));
}

extern "C" void kernel_launch(void* const* d_in, const int* in_sizes, int n_in,
                              void* d_out, int out_size, void* d_ws, size_t ws_size,
                              hipStream_t stream) {
    const float* cost = (const float*)d_in[0];
    // d_in[1] is k (always 2 for this problem; hard-coded top-2 path)
    float* out = (float*)d_out;
    topk2_disp_kernel<<<GRID, BLOCK, 0, stream>>>(cost, out);
}